// Round 11
// baseline (204.037 us; speedup 1.0000x reference)
//
#include <hip/hip_runtime.h>

namespace {

typedef float v2f __attribute__((ext_vector_type(2)));

constexpr int NTAGS = 64;
constexpr int START_T = 62;
constexpr int STOP_T = 63;
constexpr int Bc = 512;
constexpr int Lc = 512;
constexpr int HL = 256;  // half length

__device__ __forceinline__ float ror1(float x) {
  // DPP row_ror:1 (0x121): lane i <- lane (i-1)&15 within its 16-lane row.
  return __int_as_float(__builtin_amdgcn_update_dpp(
      0, __float_as_int(x), 0x121, 0xf, 0xf, true));
}

__device__ __forceinline__ float wave_sum(float v) {
#pragma unroll
  for (int off = 32; off >= 1; off >>= 1)
    v += __shfl_xor(v, off, 64);
  return v;
}

// ---------------------------------------------------------------------------
// All-VALU systolic scan. 512 one-wave blocks; each wave = 2 chains
// (cid = 2*blockIdx + (lane>>5)). cid < 512: fwd chain of batch cid;
// cid >= 512: bwd chain of batch cid-512 (R10-verified bidirectional math).
// Within a 32-lane chain: lane m (=lane&31) owns rows {2m, 2m+1} and state
// packet P = {v[2m], v[2m+1]}. Matvec = 32 rounds of (pk_fma with
// round-permuted E regs; DPP row_ror:1 packet rotate), with one
// shfl_xor(16) half-swap after round 15. No LDS in the recurrence.
// Exp-domain state; power-of-2 rescale every 8 steps (exact int Msum).
// ---------------------------------------------------------------------------
__global__ __launch_bounds__(64, 1) void crf_scan(
    const float* __restrict__ inputs,   // [B, L, 64]
    const int* __restrict__ mask,       // [B, L]
    const float* __restrict__ trans,    // [64, 64]
    float* __restrict__ hv,             // [1024, 64] final half-states
    int* __restrict__ msum_out) {       // [1024]
  const int lane = threadIdx.x;
  const int m = lane & 31;        // within-chain lane
  const int h = (lane >> 4) & 1;  // half (j in [32h, 32h+32) starts here)
  const int m16 = lane & 15;
  const int cid = blockIdx.x * 2 + (lane >> 5);
  const bool bwd = cid >= Bc;     // wave-uniform (blocks 0-255 fwd, 256-511 bwd)
  const int b = bwd ? cid - Bc : cid;
  const int i0 = 2 * m;           // owned rows i0, i0+1

  const float* pe = inputs + (size_t)b * Lc * NTAGS + i0;
  const int* mp = mask + (size_t)b * Lc;

#define FOR32(X) X(0) X(1) X(2) X(3) X(4) X(5) X(6) X(7) X(8) X(9) X(10)  \
    X(11) X(12) X(13) X(14) X(15) X(16) X(17) X(18) X(19) X(20) X(21)     \
    X(22) X(23) X(24) X(25) X(26) X(27) X(28) X(29) X(30) X(31)

  // E registers, round-permuted: at round r this lane's packet is the
  // original packet of lane j4 = (m16 - r)&15 of half h (r<16), or
  // j4 = (m16 + 17 - r)&15 of half 1-h (r>=16, after the swap).
#define DECLE(r) v2f E0_##r, E1_##r;
  FOR32(DECLE)
#define TE(I, J) __expf(bwd ? trans[(J)*NTAGS + (I)] : trans[(I)*NTAGS + (J)])
#define LOADE(r)                                                        \
  {                                                                     \
    const int jb = (r) < 16                                             \
        ? (32 * h + 2 * ((m16 - (r)) & 15))                             \
        : (32 * (1 - h) + 2 * ((m16 + 17 - (r)) & 15));                 \
    E0_##r = (v2f){TE(i0, jb), TE(i0, jb + 1)};                         \
    E1_##r = (v2f){TE(i0 + 1, jb), TE(i0 + 1, jb + 1)};                 \
  }
  FOR32(LOADE)

  // ---- init state ----
  v2f P;
  if (!bwd) {
    P = (v2f){(i0 == START_T) ? 1.0f : 0.0f,
              (i0 + 1 == START_T) ? 1.0f : 0.0f};
  } else {
    const bool gate = (mp[Lc - 1] != 0);
    const float w0 = gate ? __expf(pe[(size_t)(Lc - 1) * NTAGS]) : 1.0f;
    const float w1 = gate ? __expf(pe[(size_t)(Lc - 1) * NTAGS + 1]) : 1.0f;
    P = (v2f){__expf(trans[STOP_T * NTAGS + i0]) * w0,
              __expf(trans[STOP_T * NTAGS + i0 + 1]) * w1};
  }
  int Msum = 0;

#define ROT { P.x = ror1(P.x); P.y = ror1(P.y); }
#define RND(r) { acc0 += E0_##r * P; acc1 += E1_##r * P; }
#define SWAPP { P.x = __shfl_xor(P.x, 16, 64); P.y = __shfl_xor(P.y, 16, 64); }

#define RESCALE                                                         \
  {                                                                     \
    const int rb = __float_as_int(__shfl(P.x, 0, 32));                  \
    const unsigned e0 = ((unsigned)rb >> 23) & 0xffu;                   \
    const int d = (e0 == 0u) ? 0 : (int)e0 - 127;                       \
    Msum += d;                                                          \
    const float rs = __uint_as_float((unsigned)(127 - d) << 23);        \
    P.x *= rs;                                                          \
    P.y *= rs;                                                          \
  }

#define STEP(W, U, RESC)                                                \
  {                                                                     \
    if (RESC) RESCALE                                                   \
    v2f acc0 = E0_0 * P, acc1 = E1_0 * P;                               \
    ROT RND(1) ROT RND(2) ROT RND(3) ROT RND(4) ROT RND(5)              \
    ROT RND(6) ROT RND(7) ROT RND(8) ROT RND(9) ROT RND(10)             \
    ROT RND(11) ROT RND(12) ROT RND(13) ROT RND(14) ROT RND(15)         \
    SWAPP                                                               \
    RND(16) ROT RND(17) ROT RND(18) ROT RND(19) ROT RND(20)             \
    ROT RND(21) ROT RND(22) ROT RND(23) ROT RND(24) ROT RND(25)         \
    ROT RND(26) ROT RND(27) ROT RND(28) ROT RND(29) ROT RND(30)         \
    ROT RND(31)                                                         \
    const float s0 = acc0.x + acc0.y, s1 = acc1.x + acc1.y;             \
    v2f np = (v2f){s0 * (W).x, s1 * (W).y};                             \
    if (!allfast) {                                                     \
      /* masked steps present: v'_i = sum_j v_j (P is a permutation of  \
         the state across the 32 lanes -> reduce directly) */           \
      float sv = P.x + P.y;                                             \
      sv += __shfl_xor(sv, 1, 64);                                      \
      sv += __shfl_xor(sv, 2, 64);                                      \
      sv += __shfl_xor(sv, 4, 64);                                      \
      sv += __shfl_xor(sv, 8, 64);                                      \
      sv += __shfl_xor(sv, 16, 64);                                     \
      const float sl0 = bwd ? sv * (W).x : sv;                          \
      const float sl1 = bwd ? sv * (W).y : sv;                          \
      const int mv = (mvsh >> (U)) & 1;                                 \
      np.x = mv ? np.x : sl0;                                           \
      np.y = mv ? np.y : sl1;                                           \
    }                                                                   \
    P = np;                                                             \
  }

  // W = per-step emit weights for the two owned rows.
  // fwd step k: exp(emit[k][i0..i0+1]) (unused on masked steps).
  // bwd step k: k>=255 -> 1; else e=510-k, gated by mask[e].
  v2f wA[4], wB[4];
#define PRE(Wb, ST)                                                     \
  {                                                                     \
    _Pragma("unroll") for (int q_ = 0; q_ < 4; ++q_) {                  \
      const int k_ = (ST) + q_;                                         \
      if (!bwd) {                                                       \
        const int kk = k_ < HL ? k_ : HL - 1;                           \
        const float* pp = pe + (size_t)kk * NTAGS;                      \
        Wb[q_] = (v2f){__expf(pp[0]), __expf(pp[1])};                   \
      } else if (k_ >= HL - 1) {                                        \
        Wb[q_] = (v2f){1.0f, 1.0f};                                     \
      } else {                                                          \
        const int e_ = (Lc - 2) - k_;                                   \
        if (mp[e_] != 0) {                                              \
          const float* pp = pe + (size_t)e_ * NTAGS;                    \
          Wb[q_] = (v2f){__expf(pp[0]), __expf(pp[1])};                 \
        } else {                                                        \
          Wb[q_] = (v2f){1.0f, 1.0f};                                   \
        }                                                               \
      }                                                                 \
    }                                                                   \
  }

  PRE(wA, 0)
  for (int c = 0; c < 8; ++c) {
    const int cb = c * 32;
    const int pos = cb + m;
    const int mrow = mp[bwd ? (Lc - 1) - pos : pos];
    const unsigned long long bal = __ballot(mrow != 0);
    const bool allfast = (bal == ~0ull);
    const unsigned mvsh = (unsigned)(bal >> (lane & 32));
    for (int gp = 0; gp < 4; ++gp) {
      const int base = cb + gp * 8;
      const int u0 = gp * 8;
      PRE(wB, base + 4)
      STEP(wA[0], u0 + 0, true)
      STEP(wA[1], u0 + 1, false)
      STEP(wA[2], u0 + 2, false)
      STEP(wA[3], u0 + 3, false)
      PRE(wA, base + 8)
      STEP(wB[0], u0 + 4, false)
      STEP(wB[1], u0 + 5, false)
      STEP(wB[2], u0 + 6, false)
      STEP(wB[3], u0 + 7, false)
    }
  }

  // final rescale so the join's elementwise products stay in f32 range
  RESCALE

  // write half-state in natural j order (lane owns v[i0], v[i0+1])
  *(float2*)&hv[(size_t)cid * NTAGS + i0] = make_float2(P.x, P.y);
  if (m == 0) msum_out[cid] = Msum;
}

// ---------------------------------------------------------------------------
// Numerator score (exact): one wave per batch. (verified R7-R10)
// ---------------------------------------------------------------------------
__global__ void crf_num(const float* __restrict__ inputs,
                        const int* __restrict__ tags,
                        const int* __restrict__ mask,
                        const float* __restrict__ trans,
                        float* __restrict__ num) {
  const int b = blockIdx.x;
  const int lane = threadIdx.x;
  const float* emit_base = inputs + (size_t)b * Lc * NTAGS;
  const int* tags_b = tags + b * Lc;
  const int* mask_b = mask + b * Lc;

  float sc = 0.0f;
  for (int l = lane; l < Lc; l += 64) {
    int tl = tags_b[l];
    float mfl = (float)mask_b[l];
    if (l < Lc - 1) {
      int tn = tags_b[l + 1];
      float mfn = (float)mask_b[l + 1];
      sc += trans[tn * NTAGS + tl] * mfn +
            emit_base[(size_t)l * NTAGS + tl] * mfl;
    } else {
      sc += trans[STOP_T * NTAGS + tl] +
            emit_base[(size_t)l * NTAGS + tl] * mfl;
    }
  }
  if (lane == 0) sc += trans[tags_b[0] * NTAGS + START_T];
  float score = wave_sum(sc);
  if (lane == 0) num[b] = score;
}

// ---------------------------------------------------------------------------
// Join: partial[b] = num[b] - ( log(f . z) + (MsF+MsB) ln2 )  (verified R10)
// ---------------------------------------------------------------------------
__global__ void crf_join(const float* __restrict__ hv,
                         const int* __restrict__ msum,
                         const float* __restrict__ num,
                         float* __restrict__ partial) {
  const int b = blockIdx.x;
  const int lane = threadIdx.x;
  const float prod = hv[(size_t)b * NTAGS + lane] *
                     hv[(size_t)(b + Bc) * NTAGS + lane];
  const float sden = wave_sum(prod);
  if (lane == 0) {
    const float mf = (float)(msum[b] + msum[b + Bc]);
    const float C = fmaf(mf, -2.1219444e-4f, mf * 0.693359375f);
    partial[b] = num[b] - (__logf(sden) + C);
  }
}

__global__ void crf_reduce(const float* __restrict__ partial,
                           float* __restrict__ out) {
  const int lane = threadIdx.x;
  float s = 0.0f;
  for (int i = lane; i < Bc; i += 64) s += partial[i];
  s = wave_sum(s);
  if (lane == 0) out[0] = s;
}

}  // namespace

extern "C" void kernel_launch(void* const* d_in, const int* in_sizes, int n_in,
                              void* d_out, int out_size, void* d_ws,
                              size_t ws_size, hipStream_t stream) {
  const float* inputs = (const float*)d_in[0];
  const int* tags = (const int*)d_in[1];
  const int* mask = (const int*)d_in[2];
  const float* trans = (const float*)d_in[3];
  float* out = (float*)d_out;

  float* num = (float*)d_ws;                // [512]
  float* partial = num + Bc;                // [512]
  float* hv = partial + Bc;                 // [1024][64]
  int* msum = (int*)(hv + 2 * Bc * NTAGS);  // [1024]

  crf_scan<<<Bc, 64, 0, stream>>>(inputs, mask, trans, hv, msum);
  crf_num<<<Bc, 64, 0, stream>>>(inputs, tags, mask, trans, num);
  crf_join<<<Bc, 64, 0, stream>>>(hv, msum, num, partial);
  crf_reduce<<<1, 64, 0, stream>>>(partial, out);
}